// Round 1
// baseline (480.688 us; speedup 1.0000x reference)
//
#include <hip/hip_runtime.h>

#define N_NODES 50000
#define M_NODES 50000
#define N_EDGES 800000
#define NFEAT   300
#define NHID    256
#define NCLASS  20
#define N_IDX   5000

// ---------------------------------------------------------------------------
// GEMM1: xw = x @ W1   (50000x300) @ (300x256) -> (50000x256), fp32 vector ALU
// BM=64, BN=128, BK=16; 256 threads; per-thread 8x4 register tile.
// ---------------------------------------------------------------------------
__global__ __launch_bounds__(256) void gemm1_kernel(const float* __restrict__ x,
                                                    const float* __restrict__ W1,
                                                    float* __restrict__ xw) {
    __shared__ float xs[16][64];    // transposed x tile: xs[k][m]
    __shared__ float ws[16][128];   // W1 tile: ws[k][n]
    const int tid  = threadIdx.x;
    const int row0 = blockIdx.x * 64;
    const int col0 = blockIdx.y * 128;
    const int trow = tid >> 5;      // 0..7
    const int tcol = tid & 31;      // 0..31

    const int lm = tid >> 2;        // 0..63 row for x load
    const int lk = (tid & 3) * 4;   // 0,4,8,12
    const int wn = (tid & 31) * 4;  // 0..124 col for W1 load
    const int wk = tid >> 5;        // 0..7

    float acc[8][4];
#pragma unroll
    for (int i = 0; i < 8; ++i)
#pragma unroll
        for (int j = 0; j < 4; ++j) acc[i][j] = 0.f;

    for (int k0 = 0; k0 < 304; k0 += 16) {
        // ---- load x tile (transposed into LDS) ----
        const int row = row0 + lm;
        if (row < N_NODES && (k0 + lk + 3) < NFEAT) {
            float4 v = *(const float4*)&x[(size_t)row * NFEAT + k0 + lk];
            xs[lk + 0][lm] = v.x; xs[lk + 1][lm] = v.y;
            xs[lk + 2][lm] = v.z; xs[lk + 3][lm] = v.w;
        } else {
#pragma unroll
            for (int j = 0; j < 4; ++j) {
                int k = k0 + lk + j;
                xs[lk + j][lm] = (row < N_NODES && k < NFEAT) ? x[(size_t)row * NFEAT + k] : 0.f;
            }
        }
        // ---- load W1 tile ----
#pragma unroll
        for (int kh = 0; kh < 16; kh += 8) {
            int k = k0 + wk + kh;
            float4 v = make_float4(0.f, 0.f, 0.f, 0.f);
            if (k < NFEAT) v = *(const float4*)&W1[(size_t)k * NHID + col0 + wn];
            *(float4*)&ws[wk + kh][wn] = v;
        }
        __syncthreads();

#pragma unroll
        for (int k = 0; k < 16; ++k) {
            float a[8], b[4];
            *(float4*)&a[0] = *(const float4*)&xs[k][trow * 8];
            *(float4*)&a[4] = *(const float4*)&xs[k][trow * 8 + 4];
            *(float4*)&b[0] = *(const float4*)&ws[k][tcol * 4];
#pragma unroll
            for (int i = 0; i < 8; ++i)
#pragma unroll
                for (int j = 0; j < 4; ++j) acc[i][j] += a[i] * b[j];
        }
        __syncthreads();
    }

#pragma unroll
    for (int i = 0; i < 8; ++i) {
        int row = row0 + trow * 8 + i;
        if (row < N_NODES)
            *(float4*)&xw[(size_t)row * NHID + col0 + tcol * 4] =
                make_float4(acc[i][0], acc[i][1], acc[i][2], acc[i][3]);
    }
}

// ---------------------------------------------------------------------------
// CSR build: histogram -> hierarchical exclusive scan -> scatter
// ---------------------------------------------------------------------------
__global__ void hist_kernel(const int* __restrict__ rows, int* __restrict__ counts) {
    int e = blockIdx.x * 256 + threadIdx.x;
    if (e < N_EDGES) atomicAdd(&counts[rows[e]], 1);
}

__global__ __launch_bounds__(256) void scan_chunk_kernel(const int* __restrict__ counts,
                                                         int* __restrict__ chunk_incl,
                                                         int* __restrict__ chunk_sums, int n) {
    __shared__ int lds[256];
    int i = blockIdx.x * 256 + threadIdx.x;
    int v = (i < n) ? counts[i] : 0;
    lds[threadIdx.x] = v;
    __syncthreads();
    for (int off = 1; off < 256; off <<= 1) {
        int t = (threadIdx.x >= off) ? lds[threadIdx.x - off] : 0;
        __syncthreads();
        lds[threadIdx.x] += t;
        __syncthreads();
    }
    if (i < n) chunk_incl[i] = lds[threadIdx.x];
    if (threadIdx.x == 255) chunk_sums[blockIdx.x] = lds[255];
}

__global__ __launch_bounds__(256) void scan_sums_kernel(const int* __restrict__ chunk_sums,
                                                        int* __restrict__ chunk_off,
                                                        int* __restrict__ row_ptr_end, int nchunks) {
    __shared__ int lds[256];
    int tid = threadIdx.x;
    int v = (tid < nchunks) ? chunk_sums[tid] : 0;
    lds[tid] = v;
    __syncthreads();
    for (int off = 1; off < 256; off <<= 1) {
        int t = (tid >= off) ? lds[tid - off] : 0;
        __syncthreads();
        lds[tid] += t;
        __syncthreads();
    }
    if (tid < nchunks) chunk_off[tid] = lds[tid] - v;
    if (tid == nchunks - 1) *row_ptr_end = lds[tid];   // total edge count
}

__global__ void scan_apply_kernel(const int* __restrict__ counts,
                                  const int* __restrict__ chunk_incl,
                                  const int* __restrict__ chunk_off,
                                  int* __restrict__ row_ptr, int* __restrict__ fill, int n) {
    int i = blockIdx.x * 256 + threadIdx.x;
    if (i < n) {
        int excl = chunk_incl[i] - counts[i] + chunk_off[blockIdx.x];
        row_ptr[i] = excl;
        fill[i]    = excl;
    }
}

__global__ void scatter_kernel(const int* __restrict__ rows, const int* __restrict__ cols,
                               const float* __restrict__ vals, int* __restrict__ fill,
                               int* __restrict__ csr_col, float* __restrict__ csr_val) {
    int e = blockIdx.x * 256 + threadIdx.x;
    if (e < N_EDGES) {
        int r = rows[e];
        int p = atomicAdd(&fill[r], 1);
        csr_col[p] = cols[e];
        csr_val[p] = vals[e];
    }
}

// ---------------------------------------------------------------------------
// FN spmm: h[r] = relu(sum_j val_j * xw[col_j] + b1), one block (256 thr) / row
// ---------------------------------------------------------------------------
__global__ __launch_bounds__(256) void spmm_fn_kernel(const int* __restrict__ row_ptr,
                                                      const int* __restrict__ csr_col,
                                                      const float* __restrict__ csr_val,
                                                      const float* __restrict__ xw,
                                                      const float* __restrict__ b1,
                                                      float* __restrict__ h) {
    const int r   = blockIdx.x;
    const int tid = threadIdx.x;
    const int s = row_ptr[r], e = row_ptr[r + 1];
    float acc = 0.f;
    int j = s;
    for (; j + 3 < e; j += 4) {
        int   c0 = csr_col[j], c1 = csr_col[j + 1], c2 = csr_col[j + 2], c3 = csr_col[j + 3];
        float v0 = csr_val[j], v1 = csr_val[j + 1], v2 = csr_val[j + 2], v3 = csr_val[j + 3];
        float x0 = xw[(size_t)c0 * NHID + tid];
        float x1 = xw[(size_t)c1 * NHID + tid];
        float x2 = xw[(size_t)c2 * NHID + tid];
        float x3 = xw[(size_t)c3 * NHID + tid];
        acc += v0 * x0; acc += v1 * x1; acc += v2 * x2; acc += v3 * x3;
    }
    for (; j < e; ++j) {
        int c = csr_col[j];
        acc += csr_val[j] * xw[(size_t)c * NHID + tid];
    }
    float o = acc + b1[tid];
    h[(size_t)r * NHID + tid] = o > 0.f ? o : 0.f;
}

// ---------------------------------------------------------------------------
// GEMM2: hw = h @ W2  (50000x256)@(256x20); one thread per output element.
// ---------------------------------------------------------------------------
__global__ __launch_bounds__(256) void gemm2_kernel(const float* __restrict__ h,
                                                    const float* __restrict__ W2,
                                                    float* __restrict__ hw) {
    __shared__ float w2s[NHID * NCLASS];
    for (int i = threadIdx.x; i < NHID * NCLASS; i += 256) w2s[i] = W2[i];
    __syncthreads();
    int gid = blockIdx.x * 256 + threadIdx.x;
    if (gid >= N_NODES * NCLASS) return;
    int row = gid / NCLASS;
    int col = gid - row * NCLASS;
    const float4* hp = (const float4*)&h[(size_t)row * NHID];
    float acc = 0.f;
#pragma unroll 4
    for (int k4 = 0; k4 < NHID / 4; ++k4) {
        float4 hv = hp[k4];
        int k = k4 * 4;
        acc += hv.x * w2s[(k + 0) * NCLASS + col];
        acc += hv.y * w2s[(k + 1) * NCLASS + col];
        acc += hv.z * w2s[(k + 2) * NCLASS + col];
        acc += hv.w * w2s[(k + 3) * NCLASS + col];
    }
    hw[gid] = acc;
}

// ---------------------------------------------------------------------------
// NF spmm restricted to rows appearing in idx: mark rows, edge-parallel atomics
// ---------------------------------------------------------------------------
__global__ void mark_kernel(const int* __restrict__ idx, int* __restrict__ mark) {
    int i = blockIdx.x * 256 + threadIdx.x;
    if (i < N_IDX) mark[idx[i]] = 1;
}

__global__ void nf_scatter_kernel(const int* __restrict__ rows, const int* __restrict__ cols,
                                  const float* __restrict__ vals, const int* __restrict__ mark,
                                  const float* __restrict__ hw, float* __restrict__ logits) {
    int e = blockIdx.x * 256 + threadIdx.x;
    if (e >= N_EDGES) return;
    int r = rows[e];
    if (!mark[r]) return;
    int c = cols[e];
    float v = vals[e];
    const float* __restrict__ hp = &hw[(size_t)c * NCLASS];
#pragma unroll
    for (int j = 0; j < NCLASS; ++j) atomicAdd(&logits[(size_t)r * NCLASS + j], v * hp[j]);
}

// ---------------------------------------------------------------------------
// softmax(logits[idx[i]] + b2) -> out[i]
// ---------------------------------------------------------------------------
__global__ void softmax_kernel(const int* __restrict__ idx, const float* __restrict__ logits,
                               const float* __restrict__ b2, float* __restrict__ out) {
    int i = blockIdx.x * 256 + threadIdx.x;
    if (i >= N_IDX) return;
    int r = idx[i];
    float v[NCLASS];
    float m = -1e30f;
#pragma unroll
    for (int j = 0; j < NCLASS; ++j) {
        v[j] = logits[(size_t)r * NCLASS + j] + b2[j];
        m = fmaxf(m, v[j]);
    }
    float s = 0.f;
#pragma unroll
    for (int j = 0; j < NCLASS; ++j) {
        v[j] = __expf(v[j] - m);
        s += v[j];
    }
    float inv = 1.f / s;
#pragma unroll
    for (int j = 0; j < NCLASS; ++j) out[(size_t)i * NCLASS + j] = v[j] * inv;
}

// ---------------------------------------------------------------------------
extern "C" void kernel_launch(void* const* d_in, const int* in_sizes, int n_in,
                              void* d_out, int out_size, void* d_ws, size_t ws_size,
                              hipStream_t stream) {
    const float* x       = (const float*)d_in[0];
    const int*   fn_rows = (const int*)  d_in[1];
    const int*   fn_cols = (const int*)  d_in[2];
    const float* fn_vals = (const float*)d_in[3];
    const int*   nf_rows = (const int*)  d_in[4];
    const int*   nf_cols = (const int*)  d_in[5];
    const float* nf_vals = (const float*)d_in[6];
    const int*   idx     = (const int*)  d_in[7];
    const float* W1      = (const float*)d_in[8];
    const float* b1      = (const float*)d_in[9];
    const float* W2      = (const float*)d_in[10];
    const float* b2      = (const float*)d_in[11];
    float* out = (float*)d_out;

    // workspace layout (256B aligned)
    size_t off = 0;
    auto alloc = [&](size_t bytes) {
        void* p = (char*)d_ws + off;
        off += (bytes + 255) & ~(size_t)255;
        return p;
    };
    float* xw       = (float*)alloc((size_t)N_NODES * NHID * 4);   // 51.2 MB
    float* h        = (float*)alloc((size_t)M_NODES * NHID * 4);   // 51.2 MB
    float* hw       = (float*)alloc((size_t)M_NODES * NCLASS * 4); // 4 MB
    float* logits   = (float*)alloc((size_t)N_NODES * NCLASS * 4); // 4 MB
    int*   counts   = (int*)  alloc((size_t)M_NODES * 4);
    int*   row_ptr  = (int*)  alloc((size_t)(M_NODES + 1) * 4);
    int*   fill     = (int*)  alloc((size_t)M_NODES * 4);
    int*   csr_col  = (int*)  alloc((size_t)N_EDGES * 4);
    float* csr_val  = (float*)alloc((size_t)N_EDGES * 4);
    int*   mark     = (int*)  alloc((size_t)N_NODES * 4);
    int*   chunk_incl = (int*)alloc((size_t)M_NODES * 4);
    int*   chunk_sums = (int*)alloc(256 * 4);
    int*   chunk_off  = (int*)alloc(256 * 4);
    (void)ws_size; (void)n_in; (void)in_sizes; (void)out_size;

    const int NCHUNKS = (M_NODES + 255) / 256;  // 196
    const int EB = (N_EDGES + 255) / 256;       // 3125

    // zero what must be zero each call
    hipMemsetAsync(counts, 0, (size_t)M_NODES * 4, stream);
    hipMemsetAsync(logits, 0, (size_t)N_NODES * NCLASS * 4, stream);
    hipMemsetAsync(mark,   0, (size_t)N_NODES * 4, stream);

    // GEMM1
    gemm1_kernel<<<dim3((N_NODES + 63) / 64, NHID / 128), 256, 0, stream>>>(x, W1, xw);

    // CSR build for FN
    hist_kernel<<<EB, 256, 0, stream>>>(fn_rows, counts);
    scan_chunk_kernel<<<NCHUNKS, 256, 0, stream>>>(counts, chunk_incl, chunk_sums, M_NODES);
    scan_sums_kernel<<<1, 256, 0, stream>>>(chunk_sums, chunk_off, &row_ptr[M_NODES], NCHUNKS);
    scan_apply_kernel<<<NCHUNKS, 256, 0, stream>>>(counts, chunk_incl, chunk_off, row_ptr, fill, M_NODES);
    scatter_kernel<<<EB, 256, 0, stream>>>(fn_rows, fn_cols, fn_vals, fill, csr_col, csr_val);

    // FN spmm + bias + relu
    spmm_fn_kernel<<<M_NODES, 256, 0, stream>>>(row_ptr, csr_col, csr_val, xw, b1, h);

    // GEMM2
    gemm2_kernel<<<(N_NODES * NCLASS + 255) / 256, 256, 0, stream>>>(h, W2, hw);

    // NF spmm on marked rows only
    mark_kernel<<<(N_IDX + 255) / 256, 256, 0, stream>>>(idx, mark);
    nf_scatter_kernel<<<EB, 256, 0, stream>>>(nf_rows, nf_cols, nf_vals, mark, hw, logits);

    // softmax + gather
    softmax_kernel<<<(N_IDX + 255) / 256, 256, 0, stream>>>(idx, logits, b2, out);
}

// Round 2
// 406.093 us; speedup vs baseline: 1.1837x; 1.1837x over previous
//
#include <hip/hip_runtime.h>

#define N_NODES 50000
#define M_NODES 50000
#define N_EDGES 800000
#define NFEAT   300
#define NHID    256
#define NCLASS  20
#define N_IDX   5000
#define KTILES  10          // ceil(300/32)

typedef __attribute__((ext_vector_type(8))) short bf16x8;
typedef __attribute__((ext_vector_type(4))) float f32x4;

__device__ inline unsigned short f2bf(float f) {
    unsigned u = __float_as_uint(f);
    u += 0x7fff + ((u >> 16) & 1);          // round-to-nearest-even
    return (unsigned short)(u >> 16);
}
__device__ inline float bf2f(unsigned short h) { return __uint_as_float((unsigned)h << 16); }

// ---------------------------------------------------------------------------
// Pre-transform W1 (300x256 fp32) into fragment-ready k-tiled hi/lo bf16:
// layout [kt][col][kk] (kk in [0,32)), zero-padded for k >= 300.
// ---------------------------------------------------------------------------
__global__ __launch_bounds__(256) void prep_w1_kernel(const float* __restrict__ W1,
                                                      unsigned short* __restrict__ w1h,
                                                      unsigned short* __restrict__ w1l) {
    int id = blockIdx.x * 256 + threadIdx.x;        // 320*256 total
    if (id >= 320 * 256) return;
    int col = id & 255;
    int k   = id >> 8;                              // 0..319
    float v = (k < NFEAT) ? W1[(size_t)k * NHID + col] : 0.f;
    unsigned short hi = f2bf(v);
    unsigned short lo = f2bf(v - bf2f(hi));
    size_t off = (size_t)(k >> 5) * (256 * 32) + (size_t)col * 32 + (k & 31);
    w1h[off] = hi;
    w1l[off] = lo;
}

// ---------------------------------------------------------------------------
// GEMM1 via MFMA bf16x3: xw = x @ W1, fp32 output.
// BM=64, BN=256 (full N), 256 threads = 4 waves, each wave 64x64 output.
// A staged in LDS (fp32 -> hi/lo bf16, double-buffered, 80B-padded rows);
// B fragments loaded straight from L2-resident w1h/w1l.
// ---------------------------------------------------------------------------
__global__ __launch_bounds__(256) void gemm1_mfma_kernel(const float* __restrict__ x,
                                                         const unsigned short* __restrict__ w1h,
                                                         const unsigned short* __restrict__ w1l,
                                                         float* __restrict__ xw) {
    __shared__ unsigned short Ah[2][64 * 40];   // 40 = 32 + 8 pad (80B rows)
    __shared__ unsigned short Al[2][64 * 40];

    const int tid  = threadIdx.x;
    const int lane = tid & 63;
    const int wv   = tid >> 6;          // wave 0..3 -> col block
    const int l15  = lane & 15;
    const int g    = lane >> 4;         // k-group 0..3
    const int row0 = blockIdx.x * 64;

    // staging role: thread t loads row sr, k-chunk sc*8..sc*8+7
    const int sr = tid >> 2;            // 0..63
    const int sc = tid & 3;             // 0..3
    const bool rowok = (row0 + sr) < N_NODES;
    const float* __restrict__ xrow = x + (size_t)(row0 + sr) * NFEAT;

    float cur[8], nxt[8];
    // prologue: load k-tile 0 (k 0..31, all < 300)
    if (rowok) {
        float4 v0 = *(const float4*)&xrow[sc * 8 + 0];
        float4 v1 = *(const float4*)&xrow[sc * 8 + 4];
        cur[0] = v0.x; cur[1] = v0.y; cur[2] = v0.z; cur[3] = v0.w;
        cur[4] = v1.x; cur[5] = v1.y; cur[6] = v1.z; cur[7] = v1.w;
    } else {
#pragma unroll
        for (int j = 0; j < 8; ++j) cur[j] = 0.f;
    }

    f32x4 acc[4][4];
#pragma unroll
    for (int mf = 0; mf < 4; ++mf)
#pragma unroll
        for (int nf = 0; nf < 4; ++nf) acc[mf][nf] = (f32x4){0.f, 0.f, 0.f, 0.f};

    for (int t = 0; t < KTILES; ++t) {
        // ---- issue next-tile global loads (fly during compute) ----
        if (t < KTILES - 1) {
            const int k0 = (t + 1) * 32 + sc * 8;
            if (t + 1 < KTILES - 1) {               // full tile, k0+7 <= 287
                if (rowok) {
                    float4 v0 = *(const float4*)&xrow[k0 + 0];
                    float4 v1 = *(const float4*)&xrow[k0 + 4];
                    nxt[0] = v0.x; nxt[1] = v0.y; nxt[2] = v0.z; nxt[3] = v0.w;
                    nxt[4] = v1.x; nxt[5] = v1.y; nxt[6] = v1.z; nxt[7] = v1.w;
                } else {
#pragma unroll
                    for (int j = 0; j < 8; ++j) nxt[j] = 0.f;
                }
            } else {                                 // tail tile kt=9: k 288..319
#pragma unroll
                for (int j = 0; j < 8; ++j) {
                    int k = k0 + j;
                    nxt[j] = (rowok && k < NFEAT) ? xrow[k] : 0.f;
                }
            }
        }

        // ---- convert cur -> hi/lo, write LDS buf[t&1] ----
        {
            bf16x8 hv, lv;
#pragma unroll
            for (int j = 0; j < 8; ++j) {
                unsigned short h = f2bf(cur[j]);
                hv[j] = (short)h;
                lv[j] = (short)f2bf(cur[j] - bf2f(h));
            }
            const int wo = sr * 40 + sc * 8;
            *(bf16x8*)&Ah[t & 1][wo] = hv;
            *(bf16x8*)&Al[t & 1][wo] = lv;
        }
        __syncthreads();

        // ---- compute ----
        const int b = t & 1;
        bf16x8 ah[4], al[4];
#pragma unroll
        for (int mf = 0; mf < 4; ++mf) {
            const int ao = (mf * 16 + l15) * 40 + g * 8;
            ah[mf] = *(const bf16x8*)&Ah[b][ao];
            al[mf] = *(const bf16x8*)&Al[b][ao];
        }
        bf16x8 bh[4], bl[4];
#pragma unroll
        for (int nf = 0; nf < 4; ++nf) {
            const size_t bo = (size_t)t * 8192 + (size_t)(wv * 64 + nf * 16 + l15) * 32 + g * 8;
            bh[nf] = *(const bf16x8*)&w1h[bo];
            bl[nf] = *(const bf16x8*)&w1l[bo];
        }
#pragma unroll
        for (int mf = 0; mf < 4; ++mf)
#pragma unroll
            for (int nf = 0; nf < 4; ++nf) {
                acc[mf][nf] = __builtin_amdgcn_mfma_f32_16x16x32_bf16(ah[mf], bh[nf], acc[mf][nf], 0, 0, 0);
                acc[mf][nf] = __builtin_amdgcn_mfma_f32_16x16x32_bf16(ah[mf], bl[nf], acc[mf][nf], 0, 0, 0);
                acc[mf][nf] = __builtin_amdgcn_mfma_f32_16x16x32_bf16(al[mf], bh[nf], acc[mf][nf], 0, 0, 0);
            }
#pragma unroll
        for (int j = 0; j < 8; ++j) cur[j] = nxt[j];
    }

    // ---- epilogue: C/D layout col=lane&15, row=(lane>>4)*4+j ----
    const int colb = wv * 64;
#pragma unroll
    for (int mf = 0; mf < 4; ++mf) {
        const int rg0 = row0 + mf * 16 + g * 4;
#pragma unroll
        for (int nf = 0; nf < 4; ++nf) {
            const int cg = colb + nf * 16 + l15;
#pragma unroll
            for (int j = 0; j < 4; ++j) {
                const int rg = rg0 + j;
                if (rg < N_NODES) xw[(size_t)rg * NHID + cg] = acc[mf][nf][j];
            }
        }
    }
}

// ---------------------------------------------------------------------------
// CSR build: histogram -> hierarchical exclusive scan -> scatter
// ---------------------------------------------------------------------------
__global__ void hist_kernel(const int* __restrict__ rows, int* __restrict__ counts) {
    int e = blockIdx.x * 256 + threadIdx.x;
    if (e < N_EDGES) atomicAdd(&counts[rows[e]], 1);
}

__global__ __launch_bounds__(256) void scan_chunk_kernel(const int* __restrict__ counts,
                                                         int* __restrict__ chunk_incl,
                                                         int* __restrict__ chunk_sums, int n) {
    __shared__ int lds[256];
    int i = blockIdx.x * 256 + threadIdx.x;
    int v = (i < n) ? counts[i] : 0;
    lds[threadIdx.x] = v;
    __syncthreads();
    for (int off = 1; off < 256; off <<= 1) {
        int t = (threadIdx.x >= off) ? lds[threadIdx.x - off] : 0;
        __syncthreads();
        lds[threadIdx.x] += t;
        __syncthreads();
    }
    if (i < n) chunk_incl[i] = lds[threadIdx.x];
    if (threadIdx.x == 255) chunk_sums[blockIdx.x] = lds[255];
}

__global__ __launch_bounds__(256) void scan_sums_kernel(const int* __restrict__ chunk_sums,
                                                        int* __restrict__ chunk_off,
                                                        int* __restrict__ row_ptr_end, int nchunks) {
    __shared__ int lds[256];
    int tid = threadIdx.x;
    int v = (tid < nchunks) ? chunk_sums[tid] : 0;
    lds[tid] = v;
    __syncthreads();
    for (int off = 1; off < 256; off <<= 1) {
        int t = (tid >= off) ? lds[tid - off] : 0;
        __syncthreads();
        lds[tid] += t;
        __syncthreads();
    }
    if (tid < nchunks) chunk_off[tid] = lds[tid] - v;
    if (tid == nchunks - 1) *row_ptr_end = lds[tid];   // total edge count
}

__global__ void scan_apply_kernel(const int* __restrict__ counts,
                                  const int* __restrict__ chunk_incl,
                                  const int* __restrict__ chunk_off,
                                  int* __restrict__ row_ptr, int* __restrict__ fill, int n) {
    int i = blockIdx.x * 256 + threadIdx.x;
    if (i < n) {
        int excl = chunk_incl[i] - counts[i] + chunk_off[blockIdx.x];
        row_ptr[i] = excl;
        fill[i]    = excl;
    }
}

__global__ void scatter_kernel(const int* __restrict__ rows, const int* __restrict__ cols,
                               const float* __restrict__ vals, int* __restrict__ fill,
                               int* __restrict__ csr_col, float* __restrict__ csr_val) {
    int e = blockIdx.x * 256 + threadIdx.x;
    if (e < N_EDGES) {
        int r = rows[e];
        int p = atomicAdd(&fill[r], 1);
        csr_col[p] = cols[e];
        csr_val[p] = vals[e];
    }
}

// ---------------------------------------------------------------------------
// FN spmm: h[r] = relu(sum_j val_j * xw[col_j] + b1), one block (256 thr) / row
// ---------------------------------------------------------------------------
__global__ __launch_bounds__(256) void spmm_fn_kernel(const int* __restrict__ row_ptr,
                                                      const int* __restrict__ csr_col,
                                                      const float* __restrict__ csr_val,
                                                      const float* __restrict__ xw,
                                                      const float* __restrict__ b1,
                                                      float* __restrict__ h) {
    const int r   = blockIdx.x;
    const int tid = threadIdx.x;
    const int s = row_ptr[r], e = row_ptr[r + 1];
    float acc = 0.f;
    int j = s;
    for (; j + 3 < e; j += 4) {
        int   c0 = csr_col[j], c1 = csr_col[j + 1], c2 = csr_col[j + 2], c3 = csr_col[j + 3];
        float v0 = csr_val[j], v1 = csr_val[j + 1], v2 = csr_val[j + 2], v3 = csr_val[j + 3];
        float x0 = xw[(size_t)c0 * NHID + tid];
        float x1 = xw[(size_t)c1 * NHID + tid];
        float x2 = xw[(size_t)c2 * NHID + tid];
        float x3 = xw[(size_t)c3 * NHID + tid];
        acc += v0 * x0; acc += v1 * x1; acc += v2 * x2; acc += v3 * x3;
    }
    for (; j < e; ++j) {
        int c = csr_col[j];
        acc += csr_val[j] * xw[(size_t)c * NHID + tid];
    }
    float o = acc + b1[tid];
    h[(size_t)r * NHID + tid] = o > 0.f ? o : 0.f;
}

// ---------------------------------------------------------------------------
// GEMM2: hw = h @ W2  (50000x256)@(256x20); one thread per output element.
// ---------------------------------------------------------------------------
__global__ __launch_bounds__(256) void gemm2_kernel(const float* __restrict__ h,
                                                    const float* __restrict__ W2,
                                                    float* __restrict__ hw) {
    __shared__ float w2s[NHID * NCLASS];
    for (int i = threadIdx.x; i < NHID * NCLASS; i += 256) w2s[i] = W2[i];
    __syncthreads();
    int gid = blockIdx.x * 256 + threadIdx.x;
    if (gid >= N_NODES * NCLASS) return;
    int row = gid / NCLASS;
    int col = gid - row * NCLASS;
    const float4* hp = (const float4*)&h[(size_t)row * NHID];
    float acc = 0.f;
#pragma unroll 4
    for (int k4 = 0; k4 < NHID / 4; ++k4) {
        float4 hv = hp[k4];
        int k = k4 * 4;
        acc += hv.x * w2s[(k + 0) * NCLASS + col];
        acc += hv.y * w2s[(k + 1) * NCLASS + col];
        acc += hv.z * w2s[(k + 2) * NCLASS + col];
        acc += hv.w * w2s[(k + 3) * NCLASS + col];
    }
    hw[gid] = acc;
}

// ---------------------------------------------------------------------------
// NF spmm restricted to rows appearing in idx: mark rows, edge-parallel atomics
// ---------------------------------------------------------------------------
__global__ void mark_kernel(const int* __restrict__ idx, int* __restrict__ mark) {
    int i = blockIdx.x * 256 + threadIdx.x;
    if (i < N_IDX) mark[idx[i]] = 1;
}

__global__ void nf_scatter_kernel(const int* __restrict__ rows, const int* __restrict__ cols,
                                  const float* __restrict__ vals, const int* __restrict__ mark,
                                  const float* __restrict__ hw, float* __restrict__ logits) {
    int e = blockIdx.x * 256 + threadIdx.x;
    if (e >= N_EDGES) return;
    int r = rows[e];
    if (!mark[r]) return;
    int c = cols[e];
    float v = vals[e];
    const float* __restrict__ hp = &hw[(size_t)c * NCLASS];
#pragma unroll
    for (int j = 0; j < NCLASS; ++j) atomicAdd(&logits[(size_t)r * NCLASS + j], v * hp[j]);
}

// ---------------------------------------------------------------------------
// softmax(logits[idx[i]] + b2) -> out[i]
// ---------------------------------------------------------------------------
__global__ void softmax_kernel(const int* __restrict__ idx, const float* __restrict__ logits,
                               const float* __restrict__ b2, float* __restrict__ out) {
    int i = blockIdx.x * 256 + threadIdx.x;
    if (i >= N_IDX) return;
    int r = idx[i];
    float v[NCLASS];
    float m = -1e30f;
#pragma unroll
    for (int j = 0; j < NCLASS; ++j) {
        v[j] = logits[(size_t)r * NCLASS + j] + b2[j];
        m = fmaxf(m, v[j]);
    }
    float s = 0.f;
#pragma unroll
    for (int j = 0; j < NCLASS; ++j) {
        v[j] = __expf(v[j] - m);
        s += v[j];
    }
    float inv = 1.f / s;
#pragma unroll
    for (int j = 0; j < NCLASS; ++j) out[(size_t)i * NCLASS + j] = v[j] * inv;
}

// ---------------------------------------------------------------------------
extern "C" void kernel_launch(void* const* d_in, const int* in_sizes, int n_in,
                              void* d_out, int out_size, void* d_ws, size_t ws_size,
                              hipStream_t stream) {
    const float* x       = (const float*)d_in[0];
    const int*   fn_rows = (const int*)  d_in[1];
    const int*   fn_cols = (const int*)  d_in[2];
    const float* fn_vals = (const float*)d_in[3];
    const int*   nf_rows = (const int*)  d_in[4];
    const int*   nf_cols = (const int*)  d_in[5];
    const float* nf_vals = (const float*)d_in[6];
    const int*   idx     = (const int*)  d_in[7];
    const float* W1      = (const float*)d_in[8];
    const float* b1      = (const float*)d_in[9];
    const float* W2      = (const float*)d_in[10];
    const float* b2      = (const float*)d_in[11];
    float* out = (float*)d_out;

    // workspace layout (256B aligned)
    size_t off = 0;
    auto alloc = [&](size_t bytes) {
        void* p = (char*)d_ws + off;
        off += (bytes + 255) & ~(size_t)255;
        return p;
    };
    float* xw       = (float*)alloc((size_t)N_NODES * NHID * 4);   // 51.2 MB
    float* h        = (float*)alloc((size_t)M_NODES * NHID * 4);   // 51.2 MB
    float* hw       = (float*)alloc((size_t)M_NODES * NCLASS * 4); // 4 MB
    float* logits   = (float*)alloc((size_t)N_NODES * NCLASS * 4); // 4 MB
    int*   counts   = (int*)  alloc((size_t)M_NODES * 4);
    int*   row_ptr  = (int*)  alloc((size_t)(M_NODES + 1) * 4);
    int*   fill     = (int*)  alloc((size_t)M_NODES * 4);
    int*   csr_col  = (int*)  alloc((size_t)N_EDGES * 4);
    float* csr_val  = (float*)alloc((size_t)N_EDGES * 4);
    int*   mark     = (int*)  alloc((size_t)N_NODES * 4);
    int*   chunk_incl = (int*)alloc((size_t)M_NODES * 4);
    int*   chunk_sums = (int*)alloc(256 * 4);
    int*   chunk_off  = (int*)alloc(256 * 4);
    unsigned short* w1h = (unsigned short*)alloc((size_t)KTILES * 256 * 32 * 2);  // 160 KB
    unsigned short* w1l = (unsigned short*)alloc((size_t)KTILES * 256 * 32 * 2);  // 160 KB
    (void)ws_size; (void)n_in; (void)in_sizes; (void)out_size;

    const int NCHUNKS = (M_NODES + 255) / 256;  // 196
    const int EB = (N_EDGES + 255) / 256;       // 3125

    // zero what must be zero each call
    hipMemsetAsync(counts, 0, (size_t)M_NODES * 4, stream);
    hipMemsetAsync(logits, 0, (size_t)N_NODES * NCLASS * 4, stream);
    hipMemsetAsync(mark,   0, (size_t)N_NODES * 4, stream);

    // GEMM1 (MFMA bf16x3)
    prep_w1_kernel<<<320, 256, 0, stream>>>(W1, w1h, w1l);
    gemm1_mfma_kernel<<<(N_NODES + 63) / 64, 256, 0, stream>>>(x, w1h, w1l, xw);

    // CSR build for FN
    hist_kernel<<<EB, 256, 0, stream>>>(fn_rows, counts);
    scan_chunk_kernel<<<NCHUNKS, 256, 0, stream>>>(counts, chunk_incl, chunk_sums, M_NODES);
    scan_sums_kernel<<<1, 256, 0, stream>>>(chunk_sums, chunk_off, &row_ptr[M_NODES], NCHUNKS);
    scan_apply_kernel<<<NCHUNKS, 256, 0, stream>>>(counts, chunk_incl, chunk_off, row_ptr, fill, M_NODES);
    scatter_kernel<<<EB, 256, 0, stream>>>(fn_rows, fn_cols, fn_vals, fill, csr_col, csr_val);

    // FN spmm + bias + relu
    spmm_fn_kernel<<<M_NODES, 256, 0, stream>>>(row_ptr, csr_col, csr_val, xw, b1, h);

    // GEMM2
    gemm2_kernel<<<(N_NODES * NCLASS + 255) / 256, 256, 0, stream>>>(h, W2, hw);

    // NF spmm on marked rows only
    mark_kernel<<<(N_IDX + 255) / 256, 256, 0, stream>>>(idx, mark);
    nf_scatter_kernel<<<EB, 256, 0, stream>>>(nf_rows, nf_cols, nf_vals, mark, hw, logits);

    // softmax + gather
    softmax_kernel<<<(N_IDX + 255) / 256, 256, 0, stream>>>(idx, logits, b2, out);
}

// Round 3
// 349.049 us; speedup vs baseline: 1.3771x; 1.1634x over previous
//
#include <hip/hip_runtime.h>

#define N_NODES 50000
#define M_NODES 50000
#define N_EDGES 800000
#define NFEAT   300
#define NHID    256
#define NCLASS  20
#define N_IDX   5000
#define KTILES  10          // ceil(300/32)

typedef __attribute__((ext_vector_type(8))) short bf16x8;
typedef __attribute__((ext_vector_type(4))) float f32x4;

__device__ inline unsigned short f2bf(float f) {
    unsigned u = __float_as_uint(f);
    u += 0x7fff + ((u >> 16) & 1);          // round-to-nearest-even
    return (unsigned short)(u >> 16);
}
__device__ inline float bf2f(unsigned short h) { return __uint_as_float((unsigned)h << 16); }
__device__ inline float bflo(unsigned v) { return __uint_as_float(v << 16); }
__device__ inline float bfhi(unsigned v) { return __uint_as_float(v & 0xffff0000u); }

// ---------------------------------------------------------------------------
// Pre-transform W1 (300x256 fp32) into fragment-ready k-tiled hi/lo bf16:
// layout [kt][col][kk] (kk in [0,32)), zero-padded for k >= 300.
// ---------------------------------------------------------------------------
__global__ __launch_bounds__(256) void prep_w1_kernel(const float* __restrict__ W1,
                                                      unsigned short* __restrict__ w1h,
                                                      unsigned short* __restrict__ w1l) {
    int id = blockIdx.x * 256 + threadIdx.x;        // 320*256 total
    if (id >= 320 * 256) return;
    int col = id & 255;
    int k   = id >> 8;                              // 0..319
    float v = (k < NFEAT) ? W1[(size_t)k * NHID + col] : 0.f;
    unsigned short hi = f2bf(v);
    unsigned short lo = f2bf(v - bf2f(hi));
    size_t off = (size_t)(k >> 5) * (256 * 32) + (size_t)col * 32 + (k & 31);
    w1h[off] = hi;
    w1l[off] = lo;
}

// ---------------------------------------------------------------------------
// GEMM1 via MFMA bf16x3: xw = x @ W1, bf16 output (packed ushort).
// BM=64, BN=256 (full N), 256 threads = 4 waves, each wave 64x64 output.
// ---------------------------------------------------------------------------
__global__ __launch_bounds__(256) void gemm1_mfma_kernel(const float* __restrict__ x,
                                                         const unsigned short* __restrict__ w1h,
                                                         const unsigned short* __restrict__ w1l,
                                                         unsigned short* __restrict__ xwb) {
    __shared__ unsigned short Ah[2][64 * 40];   // 40 = 32 + 8 pad (80B rows)
    __shared__ unsigned short Al[2][64 * 40];

    const int tid  = threadIdx.x;
    const int lane = tid & 63;
    const int wv   = tid >> 6;          // wave 0..3 -> col block
    const int l15  = lane & 15;
    const int g    = lane >> 4;         // k-group 0..3
    const int row0 = blockIdx.x * 64;

    // staging role: thread t loads row sr, k-chunk sc*8..sc*8+7
    const int sr = tid >> 2;            // 0..63
    const int sc = tid & 3;             // 0..3
    const bool rowok = (row0 + sr) < N_NODES;
    const float* __restrict__ xrow = x + (size_t)(row0 + sr) * NFEAT;

    float cur[8], nxt[8];
    if (rowok) {
        float4 v0 = *(const float4*)&xrow[sc * 8 + 0];
        float4 v1 = *(const float4*)&xrow[sc * 8 + 4];
        cur[0] = v0.x; cur[1] = v0.y; cur[2] = v0.z; cur[3] = v0.w;
        cur[4] = v1.x; cur[5] = v1.y; cur[6] = v1.z; cur[7] = v1.w;
    } else {
#pragma unroll
        for (int j = 0; j < 8; ++j) cur[j] = 0.f;
    }

    f32x4 acc[4][4];
#pragma unroll
    for (int mf = 0; mf < 4; ++mf)
#pragma unroll
        for (int nf = 0; nf < 4; ++nf) acc[mf][nf] = (f32x4){0.f, 0.f, 0.f, 0.f};

    for (int t = 0; t < KTILES; ++t) {
        if (t < KTILES - 1) {
            const int k0 = (t + 1) * 32 + sc * 8;
            if (t + 1 < KTILES - 1) {
                if (rowok) {
                    float4 v0 = *(const float4*)&xrow[k0 + 0];
                    float4 v1 = *(const float4*)&xrow[k0 + 4];
                    nxt[0] = v0.x; nxt[1] = v0.y; nxt[2] = v0.z; nxt[3] = v0.w;
                    nxt[4] = v1.x; nxt[5] = v1.y; nxt[6] = v1.z; nxt[7] = v1.w;
                } else {
#pragma unroll
                    for (int j = 0; j < 8; ++j) nxt[j] = 0.f;
                }
            } else {
#pragma unroll
                for (int j = 0; j < 8; ++j) {
                    int k = k0 + j;
                    nxt[j] = (rowok && k < NFEAT) ? xrow[k] : 0.f;
                }
            }
        }

        {
            bf16x8 hv, lv;
#pragma unroll
            for (int j = 0; j < 8; ++j) {
                unsigned short h = f2bf(cur[j]);
                hv[j] = (short)h;
                lv[j] = (short)f2bf(cur[j] - bf2f(h));
            }
            const int wo = sr * 40 + sc * 8;
            *(bf16x8*)&Ah[t & 1][wo] = hv;
            *(bf16x8*)&Al[t & 1][wo] = lv;
        }
        __syncthreads();

        const int b = t & 1;
        bf16x8 ah[4], al[4];
#pragma unroll
        for (int mf = 0; mf < 4; ++mf) {
            const int ao = (mf * 16 + l15) * 40 + g * 8;
            ah[mf] = *(const bf16x8*)&Ah[b][ao];
            al[mf] = *(const bf16x8*)&Al[b][ao];
        }
        bf16x8 bh[4], bl[4];
#pragma unroll
        for (int nf = 0; nf < 4; ++nf) {
            const size_t bo = (size_t)t * 8192 + (size_t)(wv * 64 + nf * 16 + l15) * 32 + g * 8;
            bh[nf] = *(const bf16x8*)&w1h[bo];
            bl[nf] = *(const bf16x8*)&w1l[bo];
        }
#pragma unroll
        for (int mf = 0; mf < 4; ++mf)
#pragma unroll
            for (int nf = 0; nf < 4; ++nf) {
                acc[mf][nf] = __builtin_amdgcn_mfma_f32_16x16x32_bf16(ah[mf], bh[nf], acc[mf][nf], 0, 0, 0);
                acc[mf][nf] = __builtin_amdgcn_mfma_f32_16x16x32_bf16(ah[mf], bl[nf], acc[mf][nf], 0, 0, 0);
                acc[mf][nf] = __builtin_amdgcn_mfma_f32_16x16x32_bf16(al[mf], bh[nf], acc[mf][nf], 0, 0, 0);
            }
#pragma unroll
        for (int j = 0; j < 8; ++j) cur[j] = nxt[j];
    }

    // epilogue: C/D layout col=lane&15, row=(lane>>4)*4+j ; write bf16
    const int colb = wv * 64;
#pragma unroll
    for (int mf = 0; mf < 4; ++mf) {
        const int rg0 = row0 + mf * 16 + g * 4;
#pragma unroll
        for (int nf = 0; nf < 4; ++nf) {
            const int cg = colb + nf * 16 + l15;
#pragma unroll
            for (int j = 0; j < 4; ++j) {
                const int rg = rg0 + j;
                if (rg < N_NODES) xwb[(size_t)rg * NHID + cg] = f2bf(acc[mf][nf][j]);
            }
        }
    }
}

// ---------------------------------------------------------------------------
// CSR build: histogram -> hierarchical exclusive scan -> scatter
// ---------------------------------------------------------------------------
__global__ void hist_kernel(const int* __restrict__ rows, int* __restrict__ counts) {
    int e = blockIdx.x * 256 + threadIdx.x;
    if (e < N_EDGES) atomicAdd(&counts[rows[e]], 1);
}

__global__ __launch_bounds__(256) void scan_chunk_kernel(const int* __restrict__ counts,
                                                         int* __restrict__ chunk_incl,
                                                         int* __restrict__ chunk_sums, int n) {
    __shared__ int lds[256];
    int i = blockIdx.x * 256 + threadIdx.x;
    int v = (i < n) ? counts[i] : 0;
    lds[threadIdx.x] = v;
    __syncthreads();
    for (int off = 1; off < 256; off <<= 1) {
        int t = (threadIdx.x >= off) ? lds[threadIdx.x - off] : 0;
        __syncthreads();
        lds[threadIdx.x] += t;
        __syncthreads();
    }
    if (i < n) chunk_incl[i] = lds[threadIdx.x];
    if (threadIdx.x == 255) chunk_sums[blockIdx.x] = lds[255];
}

__global__ __launch_bounds__(256) void scan_sums_kernel(const int* __restrict__ chunk_sums,
                                                        int* __restrict__ chunk_off,
                                                        int* __restrict__ row_ptr_end, int nchunks) {
    __shared__ int lds[256];
    int tid = threadIdx.x;
    int v = (tid < nchunks) ? chunk_sums[tid] : 0;
    lds[tid] = v;
    __syncthreads();
    for (int off = 1; off < 256; off <<= 1) {
        int t = (tid >= off) ? lds[tid - off] : 0;
        __syncthreads();
        lds[tid] += t;
        __syncthreads();
    }
    if (tid < nchunks) chunk_off[tid] = lds[tid] - v;
    if (tid == nchunks - 1) *row_ptr_end = lds[tid];
}

__global__ void scan_apply_kernel(const int* __restrict__ counts,
                                  const int* __restrict__ chunk_incl,
                                  const int* __restrict__ chunk_off,
                                  int* __restrict__ row_ptr, int* __restrict__ fill, int n) {
    int i = blockIdx.x * 256 + threadIdx.x;
    if (i < n) {
        int excl = chunk_incl[i] - counts[i] + chunk_off[blockIdx.x];
        row_ptr[i] = excl;
        fill[i]    = excl;
    }
}

__global__ void scatter_kernel(const int* __restrict__ rows, const int* __restrict__ cols,
                               const float* __restrict__ vals, int* __restrict__ fill,
                               int* __restrict__ csr_col, float* __restrict__ csr_val) {
    int e = blockIdx.x * 256 + threadIdx.x;
    if (e < N_EDGES) {
        int r = rows[e];
        int p = atomicAdd(&fill[r], 1);
        csr_col[p] = cols[e];
        csr_val[p] = vals[e];
    }
}

// ---------------------------------------------------------------------------
// FN spmm (bf16 gather): h[r] = relu(sum_j val_j * xw[col_j] + b1)
// one block (128 thr) per row; each thread owns 2 adjacent cols (1 dword).
// ---------------------------------------------------------------------------
__global__ __launch_bounds__(128) void spmm_fn_kernel(const int* __restrict__ row_ptr,
                                                      const int* __restrict__ csr_col,
                                                      const float* __restrict__ csr_val,
                                                      const unsigned* __restrict__ xwb,
                                                      const float* __restrict__ b1,
                                                      unsigned* __restrict__ hb) {
    const int r = blockIdx.x;
    const int t = threadIdx.x;          // 0..127 -> cols 2t, 2t+1
    const int s = row_ptr[r], e = row_ptr[r + 1];
    float a0 = 0.f, a1 = 0.f;
    int j = s;
    for (; j + 3 < e; j += 4) {
        int   c0 = csr_col[j], c1 = csr_col[j + 1], c2 = csr_col[j + 2], c3 = csr_col[j + 3];
        float v0 = csr_val[j], v1 = csr_val[j + 1], v2 = csr_val[j + 2], v3 = csr_val[j + 3];
        unsigned x0 = xwb[(size_t)c0 * 128 + t];
        unsigned x1 = xwb[(size_t)c1 * 128 + t];
        unsigned x2 = xwb[(size_t)c2 * 128 + t];
        unsigned x3 = xwb[(size_t)c3 * 128 + t];
        a0 += v0 * bflo(x0); a1 += v0 * bfhi(x0);
        a0 += v1 * bflo(x1); a1 += v1 * bfhi(x1);
        a0 += v2 * bflo(x2); a1 += v2 * bfhi(x2);
        a0 += v3 * bflo(x3); a1 += v3 * bfhi(x3);
    }
    for (; j < e; ++j) {
        float v = csr_val[j];
        unsigned xv = xwb[(size_t)csr_col[j] * 128 + t];
        a0 += v * bflo(xv); a1 += v * bfhi(xv);
    }
    float2 bv = *(const float2*)&b1[t * 2];
    float o0 = fmaxf(a0 + bv.x, 0.f);
    float o1 = fmaxf(a1 + bv.y, 0.f);
    hb[(size_t)r * 128 + t] = ((unsigned)f2bf(o1) << 16) | (unsigned)f2bf(o0);
}

// ---------------------------------------------------------------------------
// GEMM2: hw = h(bf16) @ W2  (50000x256)@(256x20); one thread per output elem.
// ---------------------------------------------------------------------------
__global__ __launch_bounds__(256) void gemm2_kernel(const uint4* __restrict__ hb,
                                                    const float* __restrict__ W2,
                                                    float* __restrict__ hw) {
    __shared__ float w2s[NHID * NCLASS];
    for (int i = threadIdx.x; i < NHID * NCLASS; i += 256) w2s[i] = W2[i];
    __syncthreads();
    int gid = blockIdx.x * 256 + threadIdx.x;
    if (gid >= N_NODES * NCLASS) return;
    int row = gid / NCLASS;
    int col = gid - row * NCLASS;
    const uint4* hp = &hb[(size_t)row * 32];    // 256 bf16 = 32 x uint4
    float acc = 0.f;
#pragma unroll 4
    for (int k8 = 0; k8 < 32; ++k8) {
        uint4 hv = hp[k8];
        int k = k8 * 8;
        acc += bflo(hv.x) * w2s[(k + 0) * NCLASS + col];
        acc += bfhi(hv.x) * w2s[(k + 1) * NCLASS + col];
        acc += bflo(hv.y) * w2s[(k + 2) * NCLASS + col];
        acc += bfhi(hv.y) * w2s[(k + 3) * NCLASS + col];
        acc += bflo(hv.z) * w2s[(k + 4) * NCLASS + col];
        acc += bfhi(hv.z) * w2s[(k + 5) * NCLASS + col];
        acc += bflo(hv.w) * w2s[(k + 6) * NCLASS + col];
        acc += bfhi(hv.w) * w2s[(k + 7) * NCLASS + col];
    }
    hw[gid] = acc;
}

// ---------------------------------------------------------------------------
// NF spmm restricted to rows appearing in idx
// ---------------------------------------------------------------------------
__global__ void mark_kernel(const int* __restrict__ idx, int* __restrict__ mark) {
    int i = blockIdx.x * 256 + threadIdx.x;
    if (i < N_IDX) mark[idx[i]] = 1;
}

__global__ void nf_scatter_kernel(const int* __restrict__ rows, const int* __restrict__ cols,
                                  const float* __restrict__ vals, const int* __restrict__ mark,
                                  const float* __restrict__ hw, float* __restrict__ logits) {
    int e = blockIdx.x * 256 + threadIdx.x;
    if (e >= N_EDGES) return;
    int r = rows[e];
    if (!mark[r]) return;
    int c = cols[e];
    float v = vals[e];
    const float* __restrict__ hp = &hw[(size_t)c * NCLASS];
#pragma unroll
    for (int j = 0; j < NCLASS; ++j) atomicAdd(&logits[(size_t)r * NCLASS + j], v * hp[j]);
}

// ---------------------------------------------------------------------------
// softmax(logits[idx[i]] + b2) -> out[i]
// ---------------------------------------------------------------------------
__global__ void softmax_kernel(const int* __restrict__ idx, const float* __restrict__ logits,
                               const float* __restrict__ b2, float* __restrict__ out) {
    int i = blockIdx.x * 256 + threadIdx.x;
    if (i >= N_IDX) return;
    int r = idx[i];
    float v[NCLASS];
    float m = -1e30f;
#pragma unroll
    for (int j = 0; j < NCLASS; ++j) {
        v[j] = logits[(size_t)r * NCLASS + j] + b2[j];
        m = fmaxf(m, v[j]);
    }
    float s = 0.f;
#pragma unroll
    for (int j = 0; j < NCLASS; ++j) {
        v[j] = __expf(v[j] - m);
        s += v[j];
    }
    float inv = 1.f / s;
#pragma unroll
    for (int j = 0; j < NCLASS; ++j) out[(size_t)i * NCLASS + j] = v[j] * inv;
}

// ---------------------------------------------------------------------------
extern "C" void kernel_launch(void* const* d_in, const int* in_sizes, int n_in,
                              void* d_out, int out_size, void* d_ws, size_t ws_size,
                              hipStream_t stream) {
    const float* x       = (const float*)d_in[0];
    const int*   fn_rows = (const int*)  d_in[1];
    const int*   fn_cols = (const int*)  d_in[2];
    const float* fn_vals = (const float*)d_in[3];
    const int*   nf_rows = (const int*)  d_in[4];
    const int*   nf_cols = (const int*)  d_in[5];
    const float* nf_vals = (const float*)d_in[6];
    const int*   idx     = (const int*)  d_in[7];
    const float* W1      = (const float*)d_in[8];
    const float* b1      = (const float*)d_in[9];
    const float* W2      = (const float*)d_in[10];
    const float* b2      = (const float*)d_in[11];
    float* out = (float*)d_out;

    size_t off = 0;
    auto alloc = [&](size_t bytes) {
        void* p = (char*)d_ws + off;
        off += (bytes + 255) & ~(size_t)255;
        return p;
    };
    unsigned short* xwb = (unsigned short*)alloc((size_t)N_NODES * NHID * 2);  // 25.6 MB
    unsigned*       hb  = (unsigned*)      alloc((size_t)M_NODES * NHID * 2);  // 25.6 MB
    float* hw       = (float*)alloc((size_t)M_NODES * NCLASS * 4);             // 4 MB
    float* logits   = (float*)alloc((size_t)N_NODES * NCLASS * 4);             // 4 MB
    int*   counts   = (int*)  alloc((size_t)M_NODES * 4);
    int*   row_ptr  = (int*)  alloc((size_t)(M_NODES + 1) * 4);
    int*   fill     = (int*)  alloc((size_t)M_NODES * 4);
    int*   csr_col  = (int*)  alloc((size_t)N_EDGES * 4);
    float* csr_val  = (float*)alloc((size_t)N_EDGES * 4);
    int*   mark     = (int*)  alloc((size_t)N_NODES * 4);
    int*   chunk_incl = (int*)alloc((size_t)M_NODES * 4);
    int*   chunk_sums = (int*)alloc(256 * 4);
    int*   chunk_off  = (int*)alloc(256 * 4);
    unsigned short* w1h = (unsigned short*)alloc((size_t)KTILES * 256 * 32 * 2);
    unsigned short* w1l = (unsigned short*)alloc((size_t)KTILES * 256 * 32 * 2);
    (void)ws_size; (void)n_in; (void)in_sizes; (void)out_size;

    const int NCHUNKS = (M_NODES + 255) / 256;
    const int EB = (N_EDGES + 255) / 256;

    hipMemsetAsync(counts, 0, (size_t)M_NODES * 4, stream);
    hipMemsetAsync(logits, 0, (size_t)N_NODES * NCLASS * 4, stream);
    hipMemsetAsync(mark,   0, (size_t)N_NODES * 4, stream);

    // GEMM1 (MFMA bf16x3, bf16 output)
    prep_w1_kernel<<<320, 256, 0, stream>>>(W1, w1h, w1l);
    gemm1_mfma_kernel<<<(N_NODES + 63) / 64, 256, 0, stream>>>(x, w1h, w1l, xwb);

    // CSR build for FN
    hist_kernel<<<EB, 256, 0, stream>>>(fn_rows, counts);
    scan_chunk_kernel<<<NCHUNKS, 256, 0, stream>>>(counts, chunk_incl, chunk_sums, M_NODES);
    scan_sums_kernel<<<1, 256, 0, stream>>>(chunk_sums, chunk_off, &row_ptr[M_NODES], NCHUNKS);
    scan_apply_kernel<<<NCHUNKS, 256, 0, stream>>>(counts, chunk_incl, chunk_off, row_ptr, fill, M_NODES);
    scatter_kernel<<<EB, 256, 0, stream>>>(fn_rows, fn_cols, fn_vals, fill, csr_col, csr_val);

    // FN spmm + bias + relu (bf16 in, bf16 out)
    spmm_fn_kernel<<<M_NODES, 128, 0, stream>>>(row_ptr, csr_col, csr_val,
                                                (const unsigned*)xwb, b1, hb);

    // GEMM2 (bf16 h)
    gemm2_kernel<<<(N_NODES * NCLASS + 255) / 256, 256, 0, stream>>>((const uint4*)hb, W2, hw);

    // NF spmm on marked rows only
    mark_kernel<<<(N_IDX + 255) / 256, 256, 0, stream>>>(idx, mark);
    nf_scatter_kernel<<<EB, 256, 0, stream>>>(nf_rows, nf_cols, nf_vals, mark, hw, logits);

    // softmax + gather
    softmax_kernel<<<(N_IDX + 255) / 256, 256, 0, stream>>>(idx, logits, b2, out);
}

// Round 4
// 274.250 us; speedup vs baseline: 1.7527x; 1.2727x over previous
//
#include <hip/hip_runtime.h>

#define N_NODES 50000
#define M_NODES 50000
#define N_EDGES 800000
#define NFEAT   300
#define NHID    256
#define NCLASS  20
#define N_IDX   5000
#define KTILES  10          // ceil(300/32)

typedef __attribute__((ext_vector_type(8))) short bf16x8;
typedef __attribute__((ext_vector_type(4))) float f32x4;

__device__ inline unsigned short f2bf(float f) {
    unsigned u = __float_as_uint(f);
    u += 0x7fff + ((u >> 16) & 1);          // round-to-nearest-even
    return (unsigned short)(u >> 16);
}
__device__ inline float bf2f(unsigned short h) { return __uint_as_float((unsigned)h << 16); }
__device__ inline float bflo(unsigned v) { return __uint_as_float(v << 16); }
__device__ inline float bfhi(unsigned v) { return __uint_as_float(v & 0xffff0000u); }

// ---------------------------------------------------------------------------
// Pre-transform W1 (300x256 fp32) into fragment-ready k-tiled hi/lo bf16:
// layout [kt][col][kk] (kk in [0,32)), zero-padded for k >= 300.
// ---------------------------------------------------------------------------
__global__ __launch_bounds__(256) void prep_w1_kernel(const float* __restrict__ W1,
                                                      unsigned short* __restrict__ w1h,
                                                      unsigned short* __restrict__ w1l) {
    int id = blockIdx.x * 256 + threadIdx.x;        // 320*256 total
    if (id >= 320 * 256) return;
    int col = id & 255;
    int k   = id >> 8;                              // 0..319
    float v = (k < NFEAT) ? W1[(size_t)k * NHID + col] : 0.f;
    unsigned short hi = f2bf(v);
    unsigned short lo = f2bf(v - bf2f(hi));
    size_t off = (size_t)(k >> 5) * (256 * 32) + (size_t)col * 32 + (k & 31);
    w1h[off] = hi;
    w1l[off] = lo;
}

// ---------------------------------------------------------------------------
// GEMM1 via MFMA bf16x3: xw = x @ W1, bf16 output (packed ushort).
// BM=64, BN=256 (full N), 256 threads = 4 waves, each wave 64x64 output.
// ---------------------------------------------------------------------------
__global__ __launch_bounds__(256) void gemm1_mfma_kernel(const float* __restrict__ x,
                                                         const unsigned short* __restrict__ w1h,
                                                         const unsigned short* __restrict__ w1l,
                                                         unsigned short* __restrict__ xwb) {
    __shared__ unsigned short Ah[2][64 * 40];   // 40 = 32 + 8 pad (80B rows)
    __shared__ unsigned short Al[2][64 * 40];

    const int tid  = threadIdx.x;
    const int lane = tid & 63;
    const int wv   = tid >> 6;          // wave 0..3 -> col block
    const int l15  = lane & 15;
    const int g    = lane >> 4;         // k-group 0..3
    const int row0 = blockIdx.x * 64;

    const int sr = tid >> 2;            // 0..63
    const int sc = tid & 3;             // 0..3
    const bool rowok = (row0 + sr) < N_NODES;
    const float* __restrict__ xrow = x + (size_t)(row0 + sr) * NFEAT;

    float cur[8], nxt[8];
    if (rowok) {
        float4 v0 = *(const float4*)&xrow[sc * 8 + 0];
        float4 v1 = *(const float4*)&xrow[sc * 8 + 4];
        cur[0] = v0.x; cur[1] = v0.y; cur[2] = v0.z; cur[3] = v0.w;
        cur[4] = v1.x; cur[5] = v1.y; cur[6] = v1.z; cur[7] = v1.w;
    } else {
#pragma unroll
        for (int j = 0; j < 8; ++j) cur[j] = 0.f;
    }

    f32x4 acc[4][4];
#pragma unroll
    for (int mf = 0; mf < 4; ++mf)
#pragma unroll
        for (int nf = 0; nf < 4; ++nf) acc[mf][nf] = (f32x4){0.f, 0.f, 0.f, 0.f};

    for (int t = 0; t < KTILES; ++t) {
        if (t < KTILES - 1) {
            const int k0 = (t + 1) * 32 + sc * 8;
            if (t + 1 < KTILES - 1) {
                if (rowok) {
                    float4 v0 = *(const float4*)&xrow[k0 + 0];
                    float4 v1 = *(const float4*)&xrow[k0 + 4];
                    nxt[0] = v0.x; nxt[1] = v0.y; nxt[2] = v0.z; nxt[3] = v0.w;
                    nxt[4] = v1.x; nxt[5] = v1.y; nxt[6] = v1.z; nxt[7] = v1.w;
                } else {
#pragma unroll
                    for (int j = 0; j < 8; ++j) nxt[j] = 0.f;
                }
            } else {
#pragma unroll
                for (int j = 0; j < 8; ++j) {
                    int k = k0 + j;
                    nxt[j] = (rowok && k < NFEAT) ? xrow[k] : 0.f;
                }
            }
        }

        {
            bf16x8 hv, lv;
#pragma unroll
            for (int j = 0; j < 8; ++j) {
                unsigned short h = f2bf(cur[j]);
                hv[j] = (short)h;
                lv[j] = (short)f2bf(cur[j] - bf2f(h));
            }
            const int wo = sr * 40 + sc * 8;
            *(bf16x8*)&Ah[t & 1][wo] = hv;
            *(bf16x8*)&Al[t & 1][wo] = lv;
        }
        __syncthreads();

        const int b = t & 1;
        bf16x8 ah[4], al[4];
#pragma unroll
        for (int mf = 0; mf < 4; ++mf) {
            const int ao = (mf * 16 + l15) * 40 + g * 8;
            ah[mf] = *(const bf16x8*)&Ah[b][ao];
            al[mf] = *(const bf16x8*)&Al[b][ao];
        }
        bf16x8 bh[4], bl[4];
#pragma unroll
        for (int nf = 0; nf < 4; ++nf) {
            const size_t bo = (size_t)t * 8192 + (size_t)(wv * 64 + nf * 16 + l15) * 32 + g * 8;
            bh[nf] = *(const bf16x8*)&w1h[bo];
            bl[nf] = *(const bf16x8*)&w1l[bo];
        }
#pragma unroll
        for (int mf = 0; mf < 4; ++mf)
#pragma unroll
            for (int nf = 0; nf < 4; ++nf) {
                acc[mf][nf] = __builtin_amdgcn_mfma_f32_16x16x32_bf16(ah[mf], bh[nf], acc[mf][nf], 0, 0, 0);
                acc[mf][nf] = __builtin_amdgcn_mfma_f32_16x16x32_bf16(ah[mf], bl[nf], acc[mf][nf], 0, 0, 0);
                acc[mf][nf] = __builtin_amdgcn_mfma_f32_16x16x32_bf16(al[mf], bh[nf], acc[mf][nf], 0, 0, 0);
            }
#pragma unroll
        for (int j = 0; j < 8; ++j) cur[j] = nxt[j];
    }

    const int colb = wv * 64;
#pragma unroll
    for (int mf = 0; mf < 4; ++mf) {
        const int rg0 = row0 + mf * 16 + g * 4;
#pragma unroll
        for (int nf = 0; nf < 4; ++nf) {
            const int cg = colb + nf * 16 + l15;
#pragma unroll
            for (int j = 0; j < 4; ++j) {
                const int rg = rg0 + j;
                if (rg < N_NODES) xwb[(size_t)rg * NHID + cg] = f2bf(acc[mf][nf][j]);
            }
        }
    }
}

// ---------------------------------------------------------------------------
// CSR build: histogram -> hierarchical exclusive scan -> scatter
// ---------------------------------------------------------------------------
__global__ void hist_kernel(const int* __restrict__ rows, int* __restrict__ counts) {
    int e = blockIdx.x * 256 + threadIdx.x;
    if (e < N_EDGES) atomicAdd(&counts[rows[e]], 1);
}

// NF variant: count only edges whose output row is marked
__global__ void hist_marked_kernel(const int* __restrict__ rows, const int* __restrict__ mark,
                                   int* __restrict__ counts) {
    int e = blockIdx.x * 256 + threadIdx.x;
    if (e < N_EDGES) {
        int r = rows[e];
        if (mark[r]) atomicAdd(&counts[r], 1);
    }
}

__global__ __launch_bounds__(256) void scan_chunk_kernel(const int* __restrict__ counts,
                                                         int* __restrict__ chunk_incl,
                                                         int* __restrict__ chunk_sums, int n) {
    __shared__ int lds[256];
    int i = blockIdx.x * 256 + threadIdx.x;
    int v = (i < n) ? counts[i] : 0;
    lds[threadIdx.x] = v;
    __syncthreads();
    for (int off = 1; off < 256; off <<= 1) {
        int t = (threadIdx.x >= off) ? lds[threadIdx.x - off] : 0;
        __syncthreads();
        lds[threadIdx.x] += t;
        __syncthreads();
    }
    if (i < n) chunk_incl[i] = lds[threadIdx.x];
    if (threadIdx.x == 255) chunk_sums[blockIdx.x] = lds[255];
}

__global__ __launch_bounds__(256) void scan_sums_kernel(const int* __restrict__ chunk_sums,
                                                        int* __restrict__ chunk_off,
                                                        int* __restrict__ row_ptr_end, int nchunks) {
    __shared__ int lds[256];
    int tid = threadIdx.x;
    int v = (tid < nchunks) ? chunk_sums[tid] : 0;
    lds[tid] = v;
    __syncthreads();
    for (int off = 1; off < 256; off <<= 1) {
        int t = (tid >= off) ? lds[tid - off] : 0;
        __syncthreads();
        lds[tid] += t;
        __syncthreads();
    }
    if (tid < nchunks) chunk_off[tid] = lds[tid] - v;
    if (tid == nchunks - 1) *row_ptr_end = lds[tid];
}

__global__ void scan_apply_kernel(const int* __restrict__ counts,
                                  const int* __restrict__ chunk_incl,
                                  const int* __restrict__ chunk_off,
                                  int* __restrict__ row_ptr, int* __restrict__ fill, int n) {
    int i = blockIdx.x * 256 + threadIdx.x;
    if (i < n) {
        int excl = chunk_incl[i] - counts[i] + chunk_off[blockIdx.x];
        row_ptr[i] = excl;
        fill[i]    = excl;
    }
}

__global__ void scatter_kernel(const int* __restrict__ rows, const int* __restrict__ cols,
                               const float* __restrict__ vals, int* __restrict__ fill,
                               int* __restrict__ csr_col, float* __restrict__ csr_val) {
    int e = blockIdx.x * 256 + threadIdx.x;
    if (e < N_EDGES) {
        int r = rows[e];
        int p = atomicAdd(&fill[r], 1);
        csr_col[p] = cols[e];
        csr_val[p] = vals[e];
    }
}

__global__ void scatter_marked_kernel(const int* __restrict__ rows, const int* __restrict__ cols,
                                      const float* __restrict__ vals, const int* __restrict__ mark,
                                      int* __restrict__ fill,
                                      int* __restrict__ csr_col, float* __restrict__ csr_val) {
    int e = blockIdx.x * 256 + threadIdx.x;
    if (e < N_EDGES) {
        int r = rows[e];
        if (mark[r]) {
            int p = atomicAdd(&fill[r], 1);
            csr_col[p] = cols[e];
            csr_val[p] = vals[e];
        }
    }
}

// ---------------------------------------------------------------------------
// FN spmm (bf16 gather): h[r] = relu(sum_j val_j * xw[col_j] + b1)
// one block (128 thr) per row; each thread owns 2 adjacent cols (1 dword).
// ---------------------------------------------------------------------------
__global__ __launch_bounds__(128) void spmm_fn_kernel(const int* __restrict__ row_ptr,
                                                      const int* __restrict__ csr_col,
                                                      const float* __restrict__ csr_val,
                                                      const unsigned* __restrict__ xwb,
                                                      const float* __restrict__ b1,
                                                      unsigned* __restrict__ hb) {
    const int r = blockIdx.x;
    const int t = threadIdx.x;          // 0..127 -> cols 2t, 2t+1
    const int s = row_ptr[r], e = row_ptr[r + 1];
    float a0 = 0.f, a1 = 0.f;
    int j = s;
    for (; j + 3 < e; j += 4) {
        int   c0 = csr_col[j], c1 = csr_col[j + 1], c2 = csr_col[j + 2], c3 = csr_col[j + 3];
        float v0 = csr_val[j], v1 = csr_val[j + 1], v2 = csr_val[j + 2], v3 = csr_val[j + 3];
        unsigned x0 = xwb[(size_t)c0 * 128 + t];
        unsigned x1 = xwb[(size_t)c1 * 128 + t];
        unsigned x2 = xwb[(size_t)c2 * 128 + t];
        unsigned x3 = xwb[(size_t)c3 * 128 + t];
        a0 += v0 * bflo(x0); a1 += v0 * bfhi(x0);
        a0 += v1 * bflo(x1); a1 += v1 * bfhi(x1);
        a0 += v2 * bflo(x2); a1 += v2 * bfhi(x2);
        a0 += v3 * bflo(x3); a1 += v3 * bfhi(x3);
    }
    for (; j < e; ++j) {
        float v = csr_val[j];
        unsigned xv = xwb[(size_t)csr_col[j] * 128 + t];
        a0 += v * bflo(xv); a1 += v * bfhi(xv);
    }
    float2 bv = *(const float2*)&b1[t * 2];
    float o0 = fmaxf(a0 + bv.x, 0.f);
    float o1 = fmaxf(a1 + bv.y, 0.f);
    hb[(size_t)r * 128 + t] = ((unsigned)f2bf(o1) << 16) | (unsigned)f2bf(o0);
}

// ---------------------------------------------------------------------------
// GEMM2: hw = h(bf16) @ W2  (50000x256)@(256x20); one thread per output elem.
// ---------------------------------------------------------------------------
__global__ __launch_bounds__(256) void gemm2_kernel(const uint4* __restrict__ hb,
                                                    const float* __restrict__ W2,
                                                    float* __restrict__ hw) {
    __shared__ float w2s[NHID * NCLASS];
    for (int i = threadIdx.x; i < NHID * NCLASS; i += 256) w2s[i] = W2[i];
    __syncthreads();
    int gid = blockIdx.x * 256 + threadIdx.x;
    if (gid >= N_NODES * NCLASS) return;
    int row = gid / NCLASS;
    int col = gid - row * NCLASS;
    const uint4* hp = &hb[(size_t)row * 32];    // 256 bf16 = 32 x uint4
    float acc = 0.f;
#pragma unroll 4
    for (int k8 = 0; k8 < 32; ++k8) {
        uint4 hv = hp[k8];
        int k = k8 * 8;
        acc += bflo(hv.x) * w2s[(k + 0) * NCLASS + col];
        acc += bfhi(hv.x) * w2s[(k + 1) * NCLASS + col];
        acc += bflo(hv.y) * w2s[(k + 2) * NCLASS + col];
        acc += bfhi(hv.y) * w2s[(k + 3) * NCLASS + col];
        acc += bflo(hv.z) * w2s[(k + 4) * NCLASS + col];
        acc += bfhi(hv.z) * w2s[(k + 5) * NCLASS + col];
        acc += bflo(hv.w) * w2s[(k + 6) * NCLASS + col];
        acc += bfhi(hv.w) * w2s[(k + 7) * NCLASS + col];
    }
    hw[gid] = acc;
}

// ---------------------------------------------------------------------------
// mark rows referenced by idx
// ---------------------------------------------------------------------------
__global__ void mark_kernel(const int* __restrict__ idx, int* __restrict__ mark) {
    int i = blockIdx.x * 256 + threadIdx.x;
    if (i < N_IDX) mark[idx[i]] = 1;
}

// ---------------------------------------------------------------------------
// Fused NF-spmm + bias + softmax: one wave per idx entry.
// Edge-parallel accumulation of 20 classes, butterfly reduce, lane 0 softmax.
// ---------------------------------------------------------------------------
__global__ __launch_bounds__(64) void spmm_nf_softmax_kernel(const int* __restrict__ idx,
                                                             const int* __restrict__ row_ptr2,
                                                             const int* __restrict__ csr2_col,
                                                             const float* __restrict__ csr2_val,
                                                             const float* __restrict__ hw,
                                                             const float* __restrict__ b2,
                                                             float* __restrict__ out) {
    const int b    = blockIdx.x;
    const int lane = threadIdx.x;
    const int r = idx[b];
    const int s = row_ptr2[r], e = row_ptr2[r + 1];

    float acc[NCLASS];
#pragma unroll
    for (int k = 0; k < NCLASS; ++k) acc[k] = 0.f;

    for (int j = s + lane; j < e; j += 64) {
        int   c = csr2_col[j];
        float v = csr2_val[j];
        const float4* hp = (const float4*)&hw[(size_t)c * NCLASS];
        float4 h0 = hp[0], h1 = hp[1], h2 = hp[2], h3 = hp[3], h4 = hp[4];
        acc[0]  += v * h0.x; acc[1]  += v * h0.y; acc[2]  += v * h0.z; acc[3]  += v * h0.w;
        acc[4]  += v * h1.x; acc[5]  += v * h1.y; acc[6]  += v * h1.z; acc[7]  += v * h1.w;
        acc[8]  += v * h2.x; acc[9]  += v * h2.y; acc[10] += v * h2.z; acc[11] += v * h2.w;
        acc[12] += v * h3.x; acc[13] += v * h3.y; acc[14] += v * h3.z; acc[15] += v * h3.w;
        acc[16] += v * h4.x; acc[17] += v * h4.y; acc[18] += v * h4.z; acc[19] += v * h4.w;
    }

#pragma unroll
    for (int k = 0; k < NCLASS; ++k) {
#pragma unroll
        for (int off = 1; off < 64; off <<= 1) acc[k] += __shfl_xor(acc[k], off, 64);
    }

    if (lane == 0) {
        float v[NCLASS];
        float m = -1e30f;
#pragma unroll
        for (int k = 0; k < NCLASS; ++k) {
            v[k] = acc[k] + b2[k];
            m = fmaxf(m, v[k]);
        }
        float sum = 0.f;
#pragma unroll
        for (int k = 0; k < NCLASS; ++k) {
            v[k] = __expf(v[k] - m);
            sum += v[k];
        }
        float inv = 1.f / sum;
#pragma unroll
        for (int k = 0; k < NCLASS; ++k) out[(size_t)b * NCLASS + k] = v[k] * inv;
    }
}

// ---------------------------------------------------------------------------
extern "C" void kernel_launch(void* const* d_in, const int* in_sizes, int n_in,
                              void* d_out, int out_size, void* d_ws, size_t ws_size,
                              hipStream_t stream) {
    const float* x       = (const float*)d_in[0];
    const int*   fn_rows = (const int*)  d_in[1];
    const int*   fn_cols = (const int*)  d_in[2];
    const float* fn_vals = (const float*)d_in[3];
    const int*   nf_rows = (const int*)  d_in[4];
    const int*   nf_cols = (const int*)  d_in[5];
    const float* nf_vals = (const float*)d_in[6];
    const int*   idx     = (const int*)  d_in[7];
    const float* W1      = (const float*)d_in[8];
    const float* b1      = (const float*)d_in[9];
    const float* W2      = (const float*)d_in[10];
    const float* b2      = (const float*)d_in[11];
    float* out = (float*)d_out;

    size_t off = 0;
    auto alloc = [&](size_t bytes) {
        void* p = (char*)d_ws + off;
        off += (bytes + 255) & ~(size_t)255;
        return p;
    };
    unsigned short* xwb = (unsigned short*)alloc((size_t)N_NODES * NHID * 2);  // 25.6 MB
    unsigned*       hb  = (unsigned*)      alloc((size_t)M_NODES * NHID * 2);  // 25.6 MB
    float* hw       = (float*)alloc((size_t)M_NODES * NCLASS * 4);             // 4 MB
    int*   counts   = (int*)  alloc((size_t)M_NODES * 4);
    int*   row_ptr  = (int*)  alloc((size_t)(M_NODES + 1) * 4);
    int*   fill     = (int*)  alloc((size_t)M_NODES * 4);
    int*   csr_col  = (int*)  alloc((size_t)N_EDGES * 4);
    float* csr_val  = (float*)alloc((size_t)N_EDGES * 4);
    int*   counts2  = (int*)  alloc((size_t)N_NODES * 4);
    int*   row_ptr2 = (int*)  alloc((size_t)(N_NODES + 1) * 4);
    int*   fill2    = (int*)  alloc((size_t)N_NODES * 4);
    int*   csr2_col = (int*)  alloc((size_t)N_EDGES * 4);
    float* csr2_val = (float*)alloc((size_t)N_EDGES * 4);
    int*   mark     = (int*)  alloc((size_t)N_NODES * 4);
    int*   chunk_incl = (int*)alloc((size_t)M_NODES * 4);
    int*   chunk_sums = (int*)alloc(256 * 4);
    int*   chunk_off  = (int*)alloc(256 * 4);
    unsigned short* w1h = (unsigned short*)alloc((size_t)KTILES * 256 * 32 * 2);
    unsigned short* w1l = (unsigned short*)alloc((size_t)KTILES * 256 * 32 * 2);
    (void)ws_size; (void)n_in; (void)in_sizes; (void)out_size;

    const int NCHUNKS = (M_NODES + 255) / 256;  // 196
    const int EB = (N_EDGES + 255) / 256;       // 3125

    hipMemsetAsync(counts,  0, (size_t)M_NODES * 4, stream);
    hipMemsetAsync(counts2, 0, (size_t)N_NODES * 4, stream);
    hipMemsetAsync(mark,    0, (size_t)N_NODES * 4, stream);

    // GEMM1 (MFMA bf16x3, bf16 output)
    prep_w1_kernel<<<320, 256, 0, stream>>>(W1, w1h, w1l);
    gemm1_mfma_kernel<<<(N_NODES + 63) / 64, 256, 0, stream>>>(x, w1h, w1l, xwb);

    // CSR build for FN
    hist_kernel<<<EB, 256, 0, stream>>>(fn_rows, counts);
    scan_chunk_kernel<<<NCHUNKS, 256, 0, stream>>>(counts, chunk_incl, chunk_sums, M_NODES);
    scan_sums_kernel<<<1, 256, 0, stream>>>(chunk_sums, chunk_off, &row_ptr[M_NODES], NCHUNKS);
    scan_apply_kernel<<<NCHUNKS, 256, 0, stream>>>(counts, chunk_incl, chunk_off, row_ptr, fill, M_NODES);
    scatter_kernel<<<EB, 256, 0, stream>>>(fn_rows, fn_cols, fn_vals, fill, csr_col, csr_val);

    // FN spmm + bias + relu (bf16 in, bf16 out)
    spmm_fn_kernel<<<M_NODES, 128, 0, stream>>>(row_ptr, csr_col, csr_val,
                                                (const unsigned*)xwb, b1, hb);

    // GEMM2 (bf16 h)
    gemm2_kernel<<<(N_NODES * NCLASS + 255) / 256, 256, 0, stream>>>((const uint4*)hb, W2, hw);

    // NF CSR restricted to marked rows
    mark_kernel<<<(N_IDX + 255) / 256, 256, 0, stream>>>(idx, mark);
    hist_marked_kernel<<<EB, 256, 0, stream>>>(nf_rows, mark, counts2);
    scan_chunk_kernel<<<NCHUNKS, 256, 0, stream>>>(counts2, chunk_incl, chunk_sums, N_NODES);
    scan_sums_kernel<<<1, 256, 0, stream>>>(chunk_sums, chunk_off, &row_ptr2[N_NODES], NCHUNKS);
    scan_apply_kernel<<<NCHUNKS, 256, 0, stream>>>(counts2, chunk_incl, chunk_off, row_ptr2, fill2, N_NODES);
    scatter_marked_kernel<<<EB, 256, 0, stream>>>(nf_rows, nf_cols, nf_vals, mark, fill2, csr2_col, csr2_val);

    // fused NF spmm + bias + softmax -> out
    spmm_nf_softmax_kernel<<<N_IDX, 64, 0, stream>>>(idx, row_ptr2, csr2_col, csr2_val, hw, b2, out);
}